// Round 1
// baseline (685.299 us; speedup 1.0000x reference)
//
#include <hip/hip_runtime.h>
#include <math.h>

#define Bn   64
#define Nn   512
#define Dn   256
#define IMGn 51

// ---------------- row L2-normalize: one wave (64 lanes) per row, float4/lane ----
__global__ __launch_bounds__(256) void k_norm(const float* __restrict__ in,
                                              float* __restrict__ out) {
    int idx  = blockIdx.x * 256 + threadIdx.x;
    int row  = idx >> 6;            // Bn*Nn rows, grid covers exactly
    int lane = threadIdx.x & 63;
    const float4* src = (const float4*)(in + (size_t)row * Dn);
    float4 v = src[lane];
    float ss = v.x * v.x + v.y * v.y + v.z * v.z + v.w * v.w;
#pragma unroll
    for (int m = 1; m < 64; m <<= 1) ss += __shfl_xor(ss, m);
    float inv = 1.0f / fmaxf(sqrtf(ss), 1e-8f);
    v.x *= inv; v.y *= inv; v.z *= inv; v.w *= inv;
    ((float4*)(out + (size_t)row * Dn))[lane] = v;
}

// ---------------- masked Gram: adj[b] = mask .* (T T^T), T = Tn[b] (512x256) ----
// 128x128 tile per block, 256 thr, 8x8 regs/thread, K-chunks of 32.
__global__ __launch_bounds__(256) void k_gram(const float* __restrict__ Tn_,
                                              const int* __restrict__ noun,
                                              float* __restrict__ adj) {
    __shared__ float As[128][33];
    __shared__ float Bs[128][33];
    const int b    = blockIdx.z;
    const int row0 = blockIdx.y * 128, col0 = blockIdx.x * 128;
    const float* T = Tn_ + (size_t)b * Nn * Dn;
    const int tid = threadIdx.x;
    const int tx = tid & 15, ty = tid >> 4;
    const int lr = tid >> 1, lc = (tid & 1) * 16;   // 128 rows x 32 k per tile
    float acc[8][8] = {};
    for (int kt = 0; kt < Dn; kt += 32) {
        const float* pa = T + (size_t)(row0 + lr) * Dn + kt + lc;
        const float* pb = T + (size_t)(col0 + lr) * Dn + kt + lc;
        float4 av[4], bv[4];
#pragma unroll
        for (int q = 0; q < 4; ++q) { av[q] = ((const float4*)pa)[q]; bv[q] = ((const float4*)pb)[q]; }
#pragma unroll
        for (int q = 0; q < 4; ++q) {
            As[lr][lc+4*q+0] = av[q].x; As[lr][lc+4*q+1] = av[q].y;
            As[lr][lc+4*q+2] = av[q].z; As[lr][lc+4*q+3] = av[q].w;
            Bs[lr][lc+4*q+0] = bv[q].x; Bs[lr][lc+4*q+1] = bv[q].y;
            Bs[lr][lc+4*q+2] = bv[q].z; Bs[lr][lc+4*q+3] = bv[q].w;
        }
        __syncthreads();
#pragma unroll
        for (int k = 0; k < 32; ++k) {
            float a[8], bb[8];
#pragma unroll
            for (int i = 0; i < 8; ++i) a[i]  = As[ty*8+i][k];
#pragma unroll
            for (int j = 0; j < 8; ++j) bb[j] = Bs[tx*8+j][k];
#pragma unroll
            for (int i = 0; i < 8; ++i)
#pragma unroll
                for (int j = 0; j < 8; ++j)
                    acc[i][j] = fmaf(a[i], bb[j], acc[i][j]);
        }
        __syncthreads();
    }
    const int* nm = noun + b * Nn;
#pragma unroll
    for (int i = 0; i < 8; ++i) {
        const int r = row0 + ty*8 + i;
        float* orow = adj + ((size_t)b * Nn + r) * Nn;
#pragma unroll
        for (int j = 0; j < 8; ++j) {
            const int c = col0 + tx*8 + j;
            float m;
            if (r < IMGn)      m = (c < IMGn) ? 0.0f : (float)nm[c];
            else if (c < IMGn) m = (float)nm[r];
            else               m = 1.0f;
            orow[c] = acc[i][j] * m;
        }
    }
}

// ---------------- C = A (Mx256) * W^T (256x256) [+bias][+relu] ------------------
template<int RELU>
__global__ __launch_bounds__(256) void k_gemm_bt(const float* __restrict__ A,
                                                 const float* __restrict__ W,
                                                 const float* __restrict__ bias,
                                                 float* __restrict__ out) {
    __shared__ float As[128][33];
    __shared__ float Bs[128][33];
    const int row0 = blockIdx.y * 128, col0 = blockIdx.x * 128;
    const int tid = threadIdx.x;
    const int tx = tid & 15, ty = tid >> 4;
    const int lr = tid >> 1, lc = (tid & 1) * 16;
    float acc[8][8] = {};
    for (int kt = 0; kt < Dn; kt += 32) {
        const float* pa = A + (size_t)(row0 + lr) * Dn + kt + lc;
        const float* pb = W + (size_t)(col0 + lr) * Dn + kt + lc;
        float4 av[4], bv[4];
#pragma unroll
        for (int q = 0; q < 4; ++q) { av[q] = ((const float4*)pa)[q]; bv[q] = ((const float4*)pb)[q]; }
#pragma unroll
        for (int q = 0; q < 4; ++q) {
            As[lr][lc+4*q+0] = av[q].x; As[lr][lc+4*q+1] = av[q].y;
            As[lr][lc+4*q+2] = av[q].z; As[lr][lc+4*q+3] = av[q].w;
            Bs[lr][lc+4*q+0] = bv[q].x; Bs[lr][lc+4*q+1] = bv[q].y;
            Bs[lr][lc+4*q+2] = bv[q].z; Bs[lr][lc+4*q+3] = bv[q].w;
        }
        __syncthreads();
#pragma unroll
        for (int k = 0; k < 32; ++k) {
            float a[8], bb[8];
#pragma unroll
            for (int i = 0; i < 8; ++i) a[i]  = As[ty*8+i][k];
#pragma unroll
            for (int j = 0; j < 8; ++j) bb[j] = Bs[tx*8+j][k];
#pragma unroll
            for (int i = 0; i < 8; ++i)
#pragma unroll
                for (int j = 0; j < 8; ++j)
                    acc[i][j] = fmaf(a[i], bb[j], acc[i][j]);
        }
        __syncthreads();
    }
#pragma unroll
    for (int i = 0; i < 8; ++i) {
        const int r = row0 + ty*8 + i;
        float* orow = out + (size_t)r * Dn;
#pragma unroll
        for (int j = 0; j < 8; ++j) {
            const int c = col0 + tx*8 + j;
            float v = acc[i][j] + (bias ? bias[c] : 0.0f);
            if (RELU) v = fmaxf(v, 0.0f);
            orow[c] = v;
        }
    }
}

// ---------------- H = relu(adj[b] (512x512) * U[b] (512x256) + bias) ------------
__global__ __launch_bounds__(256) void k_gemm_adj(const float* __restrict__ adjm,
                                                  const float* __restrict__ U,
                                                  const float* __restrict__ bias,
                                                  float* __restrict__ out) {
    __shared__ float As[128][33];
    __shared__ float Bs[32][132];
    const int b    = blockIdx.z;
    const int row0 = blockIdx.y * 128, col0 = blockIdx.x * 128;
    const float* A  = adjm + (size_t)b * Nn * Nn;
    const float* Bm = U    + (size_t)b * Nn * Dn;
    const int tid = threadIdx.x;
    const int tx = tid & 15, ty = tid >> 4;
    const int lr = tid >> 1, lc = (tid & 1) * 16;   // A: 128 rows x 32 k
    const int br = tid >> 3, bc = (tid & 7) * 16;   // B: 32 rows(k) x 128 cols
    float acc[8][8] = {};
    for (int kt = 0; kt < Nn; kt += 32) {
        const float* pa = A  + (size_t)(row0 + lr) * Nn + kt + lc;
        const float* pb = Bm + (size_t)(kt + br) * Dn + col0 + bc;
        float4 av[4], bv[4];
#pragma unroll
        for (int q = 0; q < 4; ++q) { av[q] = ((const float4*)pa)[q]; bv[q] = ((const float4*)pb)[q]; }
#pragma unroll
        for (int q = 0; q < 4; ++q) {
            As[lr][lc+4*q+0] = av[q].x; As[lr][lc+4*q+1] = av[q].y;
            As[lr][lc+4*q+2] = av[q].z; As[lr][lc+4*q+3] = av[q].w;
            ((float4*)&Bs[br][bc])[q] = bv[q];
        }
        __syncthreads();
#pragma unroll
        for (int k = 0; k < 32; ++k) {
            float a[8];
#pragma unroll
            for (int i = 0; i < 8; ++i) a[i] = As[ty*8+i][k];
            float4 b0 = *(const float4*)&Bs[k][tx*8];
            float4 b1 = *(const float4*)&Bs[k][tx*8+4];
            float bb[8] = {b0.x,b0.y,b0.z,b0.w,b1.x,b1.y,b1.z,b1.w};
#pragma unroll
            for (int i = 0; i < 8; ++i)
#pragma unroll
                for (int j = 0; j < 8; ++j)
                    acc[i][j] = fmaf(a[i], bb[j], acc[i][j]);
        }
        __syncthreads();
    }
#pragma unroll
    for (int i = 0; i < 8; ++i) {
        const int r = row0 + ty*8 + i;
        float* orow = out + ((size_t)b * Nn + r) * Dn;
#pragma unroll
        for (int j = 0; j < 8; ++j) {
            const int c = col0 + tx*8 + j;
            orow[c] = fmaxf(acc[i][j] + bias[c], 0.0f);
        }
    }
}

extern "C" void kernel_launch(void* const* d_in, const int* in_sizes, int n_in,
                              void* d_out, int out_size, void* d_ws, size_t ws_size,
                              hipStream_t stream) {
    const float* input_1  = (const float*)d_in[0];
    const float* input_2  = (const float*)d_in[1];
    const int*   noun     = (const int*)d_in[3];
    const float* w0 = (const float*)d_in[4];
    const float* b0 = (const float*)d_in[5];
    const float* w1 = (const float*)d_in[6];
    const float* b1 = (const float*)d_in[7];
    const float* wf = (const float*)d_in[8];
    const float* bf = (const float*)d_in[9];
    float* out = (float*)d_out;

    const size_t ND = (size_t)Bn * Nn * Dn;          // 8,388,608 floats
    float* ws   = (float*)d_ws;
    float* bufA = ws;                                // Tn, then H1/H2 (ping)
    float* bufU = ws + ND;                           // U (pong)
    float* adj  = ws + 2 * ND;                       // Bn*Nn*Nn floats (64 MiB)

    dim3 blk(256);
    // 1) T = l2norm(input_2 rows)
    k_norm<<<dim3((Bn * Nn * 64) / 256), blk, 0, stream>>>(input_2, bufA);
    // 2) adj = mask .* (T T^T)
    k_gram<<<dim3(Nn / 128, Nn / 128, Bn), blk, 0, stream>>>(bufA, noun, adj);
    // 3) U0 = input_1 @ w0^T
    k_gemm_bt<0><<<dim3(Dn / 128, (Bn * Nn) / 128), blk, 0, stream>>>(input_1, w0, nullptr, bufU);
    // 4) H1 = relu(adj @ U0 + b0)   (overwrites T, no longer needed)
    k_gemm_adj<<<dim3(Dn / 128, Nn / 128, Bn), blk, 0, stream>>>(adj, bufU, b0, bufA);
    // 5) U1 = H1 @ w1^T
    k_gemm_bt<0><<<dim3(Dn / 128, (Bn * Nn) / 128), blk, 0, stream>>>(bufA, w1, nullptr, bufU);
    // 6) H2 = relu(adj @ U1 + b1)
    k_gemm_adj<<<dim3(Dn / 128, Nn / 128, Bn), blk, 0, stream>>>(adj, bufU, b1, bufA);
    // 7) out = relu(H2 @ wf^T + bf)
    k_gemm_bt<1><<<dim3(Dn / 128, (Bn * Nn) / 128), blk, 0, stream>>>(bufA, wf, bf, out);
}

// Round 2
// 159.690 us; speedup vs baseline: 4.2914x; 4.2914x over previous
//
#include <hip/hip_runtime.h>
#include <math.h>

#define Bn   64
#define Nn   512
#define Dn   256
#define IMGn 51

typedef __attribute__((ext_vector_type(8))) short bf16x8;
typedef __attribute__((ext_vector_type(4))) float f32x4;
typedef __attribute__((ext_vector_type(4))) unsigned short u16x4;

__device__ inline unsigned short f2b(float f) {            // fp32 -> bf16 RNE
    union { float f; unsigned u; } v; v.f = f;
    unsigned r = v.u + 0x7fffu + ((v.u >> 16) & 1u);
    return (unsigned short)(r >> 16);
}

// ---------------- fp32 -> bf16 bulk convert (float4 / thread-iter) -------------
__global__ __launch_bounds__(256) void k_cvt(const float* __restrict__ in,
                                             unsigned short* __restrict__ out, int n4) {
    int stride = gridDim.x * 256;
    for (int i = blockIdx.x * 256 + threadIdx.x; i < n4; i += stride) {
        float4 v = ((const float4*)in)[i];
        u16x4 o = { f2b(v.x), f2b(v.y), f2b(v.z), f2b(v.w) };
        ((u16x4*)out)[i] = o;
    }
}

// ---------------- row L2-normalize fp32 -> bf16, one wave per row --------------
__global__ __launch_bounds__(256) void k_norm(const float* __restrict__ in,
                                              unsigned short* __restrict__ out) {
    int idx  = blockIdx.x * 256 + threadIdx.x;
    int row  = idx >> 6;
    int lane = threadIdx.x & 63;
    float4 v = ((const float4*)(in + (size_t)row * Dn))[lane];
    float ss = v.x * v.x + v.y * v.y + v.z * v.z + v.w * v.w;
#pragma unroll
    for (int m = 1; m < 64; m <<= 1) ss += __shfl_xor(ss, m);
    float inv = 1.0f / fmaxf(sqrtf(ss), 1e-8f);
    u16x4 o = { f2b(v.x * inv), f2b(v.y * inv), f2b(v.z * inv), f2b(v.w * inv) };
    ((u16x4*)(out + (size_t)row * Dn))[lane] = o;
}

// ---------------- MFMA GEMM core: C = A(128xK) * Bt(128xK)^T -------------------
// Tile 128x128, BK=32, 4 waves (2x2), each wave 64x64 = 4x4 frags of 16x16x32.
// LDS tiles [128 rows x 32 k] bf16, linear (row stride 64 B), staged by
// global_load_lds width 16 with source-side XOR swizzle: 16B slot s of row r
// holds global slot s ^ ((r>>1)&3)  -> frag ds_read_b128 is 2-way (free).

__device__ inline void stage128x32(const unsigned short* __restrict__ src, int ldk,
                                   char* ldsbase, int tid) {
    const int wave = tid >> 6, lane = tid & 63;
#pragma unroll
    for (int it = 0; it < 2; ++it) {
        const int chunk = wave * 128 + it * 64 + lane;   // 512 chunks of 16B
        const int row = chunk >> 2, s = chunk & 3;
        const char* g = (const char*)(src + (size_t)row * ldk) + ((s ^ ((row >> 1) & 3)) << 4);
        char* l = ldsbase + (size_t)(wave * 2048 + it * 1024);   // wave-uniform base
        __builtin_amdgcn_global_load_lds((const __attribute__((address_space(1))) void*)g,
                                         (__attribute__((address_space(3))) void*)l,
                                         16, 0, 0);
    }
}

__device__ inline bf16x8 frag(const char* ldsbase, int row, int s) {
    return *(const bf16x8*)(ldsbase + row * 64 + ((s ^ ((row >> 1) & 3)) << 4));
}

enum { EPI_GRAM = 0, EPI_TRANS = 1, EPI_BIASH = 2, EPI_FINAL = 3 };

template<int EPI>
__global__ __launch_bounds__(256) void k_mfma(const unsigned short* __restrict__ Abase,
                                              const unsigned short* __restrict__ Bbase,
                                              void* __restrict__ outp,
                                              const float* __restrict__ bias,
                                              const int* __restrict__ noun,
                                              int K, int lda, int ldb, long sA, long sB) {
    extern __shared__ char smem[];
    char* As = smem;
    char* Bs = smem + 8192;
    const int tid = threadIdx.x, lane = tid & 63, wave = tid >> 6;
    const int wr = wave >> 1, wc = wave & 1;
    const int r16 = lane & 15, s = lane >> 4;
    const size_t bz = blockIdx.z;
    const unsigned short* A  = Abase + bz * sA + (size_t)blockIdx.y * 128 * lda;
    const unsigned short* Bt = Bbase + bz * sB + (size_t)blockIdx.x * 128 * ldb;

    f32x4 acc[4][4];
#pragma unroll
    for (int m = 0; m < 4; ++m)
#pragma unroll
        for (int n = 0; n < 4; ++n)
            acc[m][n] = (f32x4){0.f, 0.f, 0.f, 0.f};

    for (int kt = 0; kt < K; kt += 32) {
        stage128x32(A + kt, lda, As, tid);
        stage128x32(Bt + kt, ldb, Bs, tid);
        __syncthreads();
        bf16x8 af[4], bv[4];
#pragma unroll
        for (int m = 0; m < 4; ++m) af[m] = frag(As, wr * 64 + m * 16 + r16, s);
#pragma unroll
        for (int n = 0; n < 4; ++n) bv[n] = frag(Bs, wc * 64 + n * 16 + r16, s);
#pragma unroll
        for (int m = 0; m < 4; ++m)
#pragma unroll
            for (int n = 0; n < 4; ++n)
                acc[m][n] = __builtin_amdgcn_mfma_f32_16x16x32_bf16(af[m], bv[n], acc[m][n], 0, 0, 0);
        __syncthreads();
    }

    const int row0 = blockIdx.y * 128, col0 = blockIdx.x * 128;

    if constexpr (EPI == EPI_GRAM) {
        unsigned short* out = (unsigned short*)outp + bz * ((size_t)Nn * Nn);
        const int* nm = noun + bz * Nn;
#pragma unroll
        for (int n = 0; n < 4; ++n) {
            const int c = col0 + wc * 64 + n * 16 + r16;
            const float nmc = (c < IMGn) ? 0.f : (float)nm[c];
#pragma unroll
            for (int m = 0; m < 4; ++m)
#pragma unroll
                for (int i = 0; i < 4; ++i) {
                    const int r = row0 + wr * 64 + m * 16 + s * 4 + i;
                    float mask;
                    if (r < IMGn)      mask = nmc;                 // c<51 -> nmc==0
                    else if (c < IMGn) mask = (float)nm[r];
                    else               mask = 1.f;
                    out[(size_t)r * Nn + c] = f2b(acc[m][n][i] * mask);
                }
        }
    } else if constexpr (EPI == EPI_BIASH) {
        unsigned short* out = (unsigned short*)outp + bz * ((size_t)Nn * Dn);
#pragma unroll
        for (int n = 0; n < 4; ++n) {
            const int c = col0 + wc * 64 + n * 16 + r16;
            const float bvv = bias[c];
#pragma unroll
            for (int m = 0; m < 4; ++m)
#pragma unroll
                for (int i = 0; i < 4; ++i) {
                    const int r = row0 + wr * 64 + m * 16 + s * 4 + i;
                    out[(size_t)r * Dn + c] = f2b(fmaxf(acc[m][n][i] + bvv, 0.f));
                }
        }
    } else if constexpr (EPI == EPI_FINAL) {
        float* out = (float*)outp;
#pragma unroll
        for (int n = 0; n < 4; ++n) {
            const int c = col0 + wc * 64 + n * 16 + r16;
            const float bvv = bias[c];
#pragma unroll
            for (int m = 0; m < 4; ++m)
#pragma unroll
                for (int i = 0; i < 4; ++i) {
                    const int r = row0 + wr * 64 + m * 16 + s * 4 + i;
                    out[(size_t)r * Dn + c] = fmaxf(acc[m][n][i] + bvv, 0.f);
                }
        }
    } else {  // EPI_TRANS: out Ut[b][c][r_local], via padded-LDS transpose bounce
        unsigned short* lt = (unsigned short*)smem;          // [128 cols][136]
#pragma unroll
        for (int n = 0; n < 4; ++n)
#pragma unroll
            for (int m = 0; m < 4; ++m)
#pragma unroll
                for (int i = 0; i < 4; ++i) {
                    const int ct = wc * 64 + n * 16 + r16;
                    const int rt = wr * 64 + m * 16 + s * 4 + i;
                    lt[ct * 136 + rt] = f2b(acc[m][n][i]);
                }
        __syncthreads();
        const int bm = blockIdx.y;
        const size_t bb = bm >> 2;
        const int rl0 = (bm & 3) * 128;
        unsigned short* out = (unsigned short*)outp + bb * ((size_t)Dn * Nn);
        const int ct = tid >> 1, h = tid & 1;
        const bf16x8* srcv = (const bf16x8*)(smem + ((size_t)ct * 136 + h * 64) * 2);
        bf16x8* dstv = (bf16x8*)(out + (size_t)(col0 + ct) * Nn + rl0 + h * 64);
#pragma unroll
        for (int q = 0; q < 8; ++q) dstv[q] = srcv[q];
    }
}

extern "C" void kernel_launch(void* const* d_in, const int* in_sizes, int n_in,
                              void* d_out, int out_size, void* d_ws, size_t ws_size,
                              hipStream_t stream) {
    const float* input_1 = (const float*)d_in[0];
    const float* input_2 = (const float*)d_in[1];
    const int*   noun    = (const int*)d_in[3];
    const float* w0 = (const float*)d_in[4];
    const float* b0 = (const float*)d_in[5];
    const float* w1 = (const float*)d_in[6];
    const float* b1 = (const float*)d_in[7];
    const float* wf = (const float*)d_in[8];
    const float* bf = (const float*)d_in[9];

    unsigned short* ws  = (unsigned short*)d_ws;
    unsigned short* T   = ws;                    // 64*512*256
    unsigned short* A0  = ws + 8388608;          // input_1 bf16
    unsigned short* adj = ws + 16777216;         // 64*512*512
    unsigned short* Ut  = ws + 33554432;         // 64*256*512
    unsigned short* H1  = ws + 41943040;
    unsigned short* H2  = ws + 50331648;
    unsigned short* w0b = ws + 58720256;
    unsigned short* w1b = w0b + 65536;
    unsigned short* wfb = w1b + 65536;

    dim3 blk(256);
    k_cvt<<<2048, blk, 0, stream>>>(input_1, A0, 2097152);
    k_cvt<<<64,   blk, 0, stream>>>(w0, w0b, 16384);
    k_cvt<<<64,   blk, 0, stream>>>(w1, w1b, 16384);
    k_cvt<<<64,   blk, 0, stream>>>(wf, wfb, 16384);
    k_norm<<<8192, blk, 0, stream>>>(input_2, T);

    // adj = mask .* (T T^T)                      M=N=512/batch, K=256
    k_mfma<EPI_GRAM><<<dim3(4, 4, Bn), blk, 16384, stream>>>(
        T, T, adj, nullptr, noun, 256, 256, 256, (long)Nn * Dn, (long)Nn * Dn);
    // Ut0 = (input_1 @ w0^T)^T                   M=32768 flat, N=256, K=256
    k_mfma<EPI_TRANS><<<dim3(2, 256, 1), blk, 34816, stream>>>(
        A0, w0b, Ut, nullptr, nullptr, 256, 256, 256, 0, 0);
    // H1 = relu(adj @ Ut0^T + b0)                M=512/batch, N=256, K=512
    k_mfma<EPI_BIASH><<<dim3(2, 4, Bn), blk, 16384, stream>>>(
        adj, Ut, H1, b0, nullptr, 512, 512, 512, (long)Nn * Nn, (long)Dn * Nn);
    // Ut1 = (H1 @ w1^T)^T
    k_mfma<EPI_TRANS><<<dim3(2, 256, 1), blk, 34816, stream>>>(
        H1, w1b, Ut, nullptr, nullptr, 256, 256, 256, 0, 0);
    // H2 = relu(adj @ Ut1^T + b1)
    k_mfma<EPI_BIASH><<<dim3(2, 4, Bn), blk, 16384, stream>>>(
        adj, Ut, H2, b1, nullptr, 512, 512, 512, (long)Nn * Nn, (long)Dn * Nn);
    // out = relu(H2 @ wf^T + bf)  (fp32 out)
    k_mfma<EPI_FINAL><<<dim3(2, 256, 1), blk, 16384, stream>>>(
        H2, wfb, d_out, bf, nullptr, 256, 256, 256, 0, 0);
}